// Round 1
// baseline (115.138 us; speedup 1.0000x reference)
//
#include <hip/hip_runtime.h>
#include <math.h>

#define EDIM 128
#define HDIM 256
#define NDIM 512
#define BDIM 2
#define LN_EPS 1e-5f

// Kernel 1: per-row LayerNorm + dual projection.
//   a[row][h] = hn(row) . W1[0:E, h]
//   b[row][h] = hn(row) . W1[E:2E, h] + b1[h]   (b1 folded in)
__global__ __launch_bounds__(256) void k_ln_proj(
    const float* __restrict__ hptr, const float* __restrict__ gamma,
    const float* __restrict__ beta, const float* __restrict__ W1,
    const float* __restrict__ b1, float* __restrict__ a_out,
    float* __restrict__ b_out)
{
    __shared__ float raw[EDIM];
    __shared__ float hn[EDIM];
    const int row = blockIdx.x;           // 0..B*N-1
    const int t = threadIdx.x;            // 0..255
    const float* hrow = hptr + row * EDIM;
    if (t < EDIM) raw[t] = hrow[t];
    __syncthreads();
    // redundant mean/var via broadcast LDS reads (cheap, no reduction plumbing)
    float s = 0.f, ss = 0.f;
    #pragma unroll
    for (int e = 0; e < EDIM; ++e) { float v = raw[e]; s += v; ss += v * v; }
    const float mu = s * (1.0f / EDIM);
    const float var = ss * (1.0f / EDIM) - mu * mu;
    const float rs = rsqrtf(var + LN_EPS);
    if (t < EDIM) hn[t] = (raw[t] - mu) * rs * gamma[t] + beta[t];
    __syncthreads();
    float sa = 0.f, sb = 0.f;
    #pragma unroll 4
    for (int e = 0; e < EDIM; ++e) {
        const float hv = hn[e];
        sa += hv * W1[e * HDIM + t];            // coalesced across t
        sb += hv * W1[(EDIM + e) * HDIM + t];
    }
    a_out[row * HDIM + t] = sa;
    b_out[row * HDIM + t] = sb + b1[t];
}

// Kernel 2: l[b,i,j] = sum_h gelu(a[b,i,h] + b[b,j,h]) * w2[h] + b2
// 16x16 (i,j) tile per 256-thread block.
#define TI 16
#define PAD 260   // float stride; keeps float4 LDS reads conflict-free

__device__ __forceinline__ float gelu_exact(float z) {
    return 0.5f * z * (1.0f + erff(z * 0.70710678118f));
}

__global__ __launch_bounds__(256) void k_pair(
    const float* __restrict__ a, const float* __restrict__ bpb,
    const float* __restrict__ w2, const float* __restrict__ b2,
    float* __restrict__ out)
{
    __shared__ float a_s[TI][PAD];
    __shared__ float b_s[TI][PAD];
    __shared__ float w2_s[HDIM];
    const int blk = blockIdx.x;           // bb*1024 + bi*32 + bj
    const int bb = blk >> 10;
    const int bi = (blk >> 5) & 31;
    const int bj = blk & 31;
    const int tid = threadIdx.x;

    const float* arow = a + (bb * NDIM + bi * TI) * HDIM;
    const float* brow = bpb + (bb * NDIM + bj * TI) * HDIM;
    #pragma unroll
    for (int idx = tid; idx < TI * (HDIM / 4); idx += 256) {
        const int r = idx >> 6;           // HDIM/4 = 64 float4 per row
        const int c = idx & 63;
        const float4 va = *(const float4*)(arow + r * HDIM + c * 4);
        const float4 vb = *(const float4*)(brow + r * HDIM + c * 4);
        *(float4*)&a_s[r][c * 4] = va;
        *(float4*)&b_s[r][c * 4] = vb;
    }
    if (tid < HDIM / 4) ((float4*)w2_s)[tid] = ((const float4*)w2)[tid];
    __syncthreads();

    const int ti = tid >> 4, tj = tid & 15;
    const float* ap = a_s[ti];
    const float* bp = b_s[tj];
    float acc = 0.f;
    #pragma unroll 4
    for (int hh = 0; hh < HDIM; hh += 4) {
        const float4 av = *(const float4*)(ap + hh);
        const float4 bv = *(const float4*)(bp + hh);
        const float4 wv = *(const float4*)(w2_s + hh);
        acc += wv.x * gelu_exact(av.x + bv.x);
        acc += wv.y * gelu_exact(av.y + bv.y);
        acc += wv.z * gelu_exact(av.z + bv.z);
        acc += wv.w * gelu_exact(av.w + bv.w);
    }
    const int i = bi * TI + ti;
    const int j = bj * TI + tj;
    out[(bb * NDIM + i) * NDIM + j] = acc + b2[0];
}

// Kernel 3: in-place symmetrize out = 0.5*(l + l^T). Each unordered pair
// (i<j) handled by exactly one thread; diagonal unchanged.
__global__ __launch_bounds__(256) void k_sym(float* __restrict__ out) {
    const int idx = blockIdx.x * 256 + threadIdx.x;   // over B*N*N
    const int i = (idx >> 9) & (NDIM - 1);
    const int j = idx & (NDIM - 1);
    if (i < j) {
        const int tidx = (idx & ~((NDIM * NDIM) - 1)) | (j << 9) | i;
        const float x = out[idx];
        const float y = out[tidx];
        const float m = 0.5f * (x + y);
        out[idx] = m;
        out[tidx] = m;
    }
}

extern "C" void kernel_launch(void* const* d_in, const int* in_sizes, int n_in,
                              void* d_out, int out_size, void* d_ws, size_t ws_size,
                              hipStream_t stream) {
    const float* hptr  = (const float*)d_in[0];
    const float* gamma = (const float*)d_in[1];
    const float* beta  = (const float*)d_in[2];
    const float* W1    = (const float*)d_in[3];
    const float* b1    = (const float*)d_in[4];
    const float* w2    = (const float*)d_in[5];
    const float* b2    = (const float*)d_in[6];
    float* out = (float*)d_out;

    float* a_ws = (float*)d_ws;                          // B*N*H floats = 1 MB
    float* b_ws = a_ws + BDIM * NDIM * HDIM;             // 1 MB more

    k_ln_proj<<<BDIM * NDIM, 256, 0, stream>>>(hptr, gamma, beta, W1, b1, a_ws, b_ws);
    k_pair<<<BDIM * (NDIM / TI) * (NDIM / TI), 256, 0, stream>>>(a_ws, b_ws, w2, b2, out);
    k_sym<<<(BDIM * NDIM * NDIM) / 256, 256, 0, stream>>>(out);
}

// Round 2
// 61.036 us; speedup vs baseline: 1.8864x; 1.8864x over previous
//
#include <hip/hip_runtime.h>
#include <math.h>

#define EDIM 128
#define HDIM 256
#define NDIM 512
#define BDIM 2
#define LN_EPS 1e-5f

// Kernel 1: per-row LayerNorm + dual projection.
//   a[row][h] = hn(row) . W1[0:E, h]
//   b[row][h] = hn(row) . W1[E:2E, h] + b1[h]   (b1 folded in)
__global__ __launch_bounds__(256) void k_ln_proj(
    const float* __restrict__ hptr, const float* __restrict__ gamma,
    const float* __restrict__ beta, const float* __restrict__ W1,
    const float* __restrict__ b1, float* __restrict__ a_out,
    float* __restrict__ b_out)
{
    __shared__ float raw[EDIM];
    __shared__ float hn[EDIM];
    const int row = blockIdx.x;           // 0..B*N-1
    const int t = threadIdx.x;            // 0..255
    const float* hrow = hptr + row * EDIM;
    if (t < EDIM) raw[t] = hrow[t];
    __syncthreads();
    float s = 0.f, ss = 0.f;
    #pragma unroll
    for (int e = 0; e < EDIM; ++e) { float v = raw[e]; s += v; ss += v * v; }
    const float mu = s * (1.0f / EDIM);
    const float var = ss * (1.0f / EDIM) - mu * mu;
    const float rs = rsqrtf(var + LN_EPS);
    if (t < EDIM) hn[t] = (raw[t] - mu) * rs * gamma[t] + beta[t];
    __syncthreads();
    float sa = 0.f, sb = 0.f;
    #pragma unroll 4
    for (int e = 0; e < EDIM; ++e) {
        const float hv = hn[e];
        sa += hv * W1[e * HDIM + t];            // coalesced across t
        sb += hv * W1[(EDIM + e) * HDIM + t];
    }
    a_out[row * HDIM + t] = sa;
    b_out[row * HDIM + t] = sb + b1[t];
}

// Fast exact-enough GELU: tanh-form evaluated as z * sigmoid(k*(z+0.044715 z^3))
// with log2(e) folded in; uses hw v_exp_f32 + v_rcp_f32.
// max |err| vs exact erf-GELU ~3e-4 per element.
__device__ __forceinline__ float gelu_fast(float z) {
    const float z2 = z * z;
    const float q  = fmaf(-0.10294826f, z2, -2.3022082f);  // c1=-2*0.79788456*log2e, c2=c1*0.044715
    const float e  = __builtin_amdgcn_exp2f(z * q);        // exp2 overflow->inf is handled by rcp->0
    const float r  = __builtin_amdgcn_rcpf(1.0f + e);
    return z * r;
}

// Kernel 2: l[b,i,j] = sum_h gelu(a[b,i,h] + b[b,j,h]) * w2[h] + b2
// 16x16 (i,j) tile per 256-thread block.
#define TI 16
#define PAD 260   // float stride; keeps float4 LDS reads conflict-free

__global__ __launch_bounds__(256) void k_pair(
    const float* __restrict__ a, const float* __restrict__ bpb,
    const float* __restrict__ w2, const float* __restrict__ b2,
    float* __restrict__ out)
{
    __shared__ float a_s[TI][PAD];
    __shared__ float b_s[TI][PAD];
    __shared__ float w2_s[HDIM];
    const int blk = blockIdx.x;           // bb*1024 + bi*32 + bj
    const int bb = blk >> 10;
    const int bi = (blk >> 5) & 31;
    const int bj = blk & 31;
    const int tid = threadIdx.x;

    const float* arow = a + (bb * NDIM + bi * TI) * HDIM;
    const float* brow = bpb + (bb * NDIM + bj * TI) * HDIM;
    #pragma unroll
    for (int idx = tid; idx < TI * (HDIM / 4); idx += 256) {
        const int r = idx >> 6;           // HDIM/4 = 64 float4 per row
        const int c = idx & 63;
        const float4 va = *(const float4*)(arow + r * HDIM + c * 4);
        const float4 vb = *(const float4*)(brow + r * HDIM + c * 4);
        *(float4*)&a_s[r][c * 4] = va;
        *(float4*)&b_s[r][c * 4] = vb;
    }
    if (tid < HDIM / 4) ((float4*)w2_s)[tid] = ((const float4*)w2)[tid];
    __syncthreads();

    const int ti = tid >> 4, tj = tid & 15;
    const float* ap = a_s[ti];
    const float* bp = b_s[tj];
    float acc0 = 0.f, acc1 = 0.f, acc2 = 0.f, acc3 = 0.f;
    #pragma unroll 8
    for (int hh = 0; hh < HDIM; hh += 4) {
        const float4 av = *(const float4*)(ap + hh);
        const float4 bv = *(const float4*)(bp + hh);
        const float4 wv = *(const float4*)(w2_s + hh);
        acc0 = fmaf(wv.x, gelu_fast(av.x + bv.x), acc0);
        acc1 = fmaf(wv.y, gelu_fast(av.y + bv.y), acc1);
        acc2 = fmaf(wv.z, gelu_fast(av.z + bv.z), acc2);
        acc3 = fmaf(wv.w, gelu_fast(av.w + bv.w), acc3);
    }
    const int i = bi * TI + ti;
    const int j = bj * TI + tj;
    out[(bb * NDIM + i) * NDIM + j] = ((acc0 + acc1) + (acc2 + acc3)) + b2[0];
}

// Kernel 3: symmetrize out = 0.5*(l + l^T) via 32x32 LDS tile transpose.
// One block per unordered tile pair (ti<=tj); coalesced reads AND writes.
__global__ __launch_bounds__(256) void k_sym(float* __restrict__ out) {
    __shared__ float Ta[32][33];
    __shared__ float Tb[32][33];
    const int blk = blockIdx.x;           // b*256 + ti*16 + tj
    const int b  = blk >> 8;
    const int ti = (blk >> 4) & 15;
    const int tj = blk & 15;
    if (tj < ti) return;                  // upper triangle only
    float* base = out + b * NDIM * NDIM;
    const int tx = threadIdx.x & 31;
    const int ty = threadIdx.x >> 5;      // 0..7
    #pragma unroll
    for (int r = ty; r < 32; r += 8) {
        Ta[r][tx] = base[(ti * 32 + r) * NDIM + tj * 32 + tx];
        Tb[r][tx] = base[(tj * 32 + r) * NDIM + ti * 32 + tx];
    }
    __syncthreads();
    #pragma unroll
    for (int r = ty; r < 32; r += 8) {
        base[(ti * 32 + r) * NDIM + tj * 32 + tx] = 0.5f * (Ta[r][tx] + Tb[tx][r]);
    }
    if (ti != tj) {
        #pragma unroll
        for (int r = ty; r < 32; r += 8) {
            base[(tj * 32 + r) * NDIM + ti * 32 + tx] = 0.5f * (Tb[r][tx] + Ta[tx][r]);
        }
    }
}

extern "C" void kernel_launch(void* const* d_in, const int* in_sizes, int n_in,
                              void* d_out, int out_size, void* d_ws, size_t ws_size,
                              hipStream_t stream) {
    const float* hptr  = (const float*)d_in[0];
    const float* gamma = (const float*)d_in[1];
    const float* beta  = (const float*)d_in[2];
    const float* W1    = (const float*)d_in[3];
    const float* b1    = (const float*)d_in[4];
    const float* w2    = (const float*)d_in[5];
    const float* b2    = (const float*)d_in[6];
    float* out = (float*)d_out;

    float* a_ws = (float*)d_ws;                          // B*N*H floats = 1 MB
    float* b_ws = a_ws + BDIM * NDIM * HDIM;             // 1 MB more

    k_ln_proj<<<BDIM * NDIM, 256, 0, stream>>>(hptr, gamma, beta, W1, b1, a_ws, b_ws);
    k_pair<<<BDIM * (NDIM / TI) * (NDIM / TI), 256, 0, stream>>>(a_ws, b_ws, w2, b2, out);
    k_sym<<<BDIM * 256, 256, 0, stream>>>(out);
}

// Round 4
// 57.696 us; speedup vs baseline: 1.9956x; 1.0579x over previous
//
#include <hip/hip_runtime.h>
#include <math.h>

#define EDIM 128
#define HDIM 256
#define NDIM 512
#define BDIM 2
#define LN_EPS 1e-5f

// Kernel 1: LayerNorm + dual projection, 4 rows per block (1 wave per row).
//   a[row][h] = hn(row) . W1[0:E, h]
//   b[row][h] = hn(row) . W1[E:2E, h] + b1[h]
__global__ __launch_bounds__(256) void k_ln_proj(
    const float* __restrict__ hptr, const float* __restrict__ gamma,
    const float* __restrict__ beta, const float* __restrict__ W1,
    const float* __restrict__ b1, float* __restrict__ a_out,
    float* __restrict__ b_out)
{
    __shared__ float hn_s[4][EDIM];
    const int tid = threadIdx.x;
    const int r = tid >> 6;            // 0..3 (row within block)
    const int lane = tid & 63;
    const int row0 = blockIdx.x * 4;
    const float2 v = *(const float2*)(hptr + (row0 + r) * EDIM + lane * 2);
    float s  = v.x + v.y;
    float ss = v.x * v.x + v.y * v.y;
    #pragma unroll
    for (int k = 32; k >= 1; k >>= 1) {
        s  += __shfl_xor(s, k, 64);
        ss += __shfl_xor(ss, k, 64);
    }
    const float mu  = s * (1.0f / EDIM);
    const float var = ss * (1.0f / EDIM) - mu * mu;
    const float rs  = rsqrtf(var + LN_EPS);
    const float2 g2 = *(const float2*)(gamma + lane * 2);
    const float2 be = *(const float2*)(beta + lane * 2);
    hn_s[r][lane * 2]     = (v.x - mu) * rs * g2.x + be.x;
    hn_s[r][lane * 2 + 1] = (v.y - mu) * rs * g2.y + be.y;
    __syncthreads();
    float sa0 = 0.f, sa1 = 0.f, sa2 = 0.f, sa3 = 0.f;
    float sb0 = 0.f, sb1 = 0.f, sb2 = 0.f, sb3 = 0.f;
    #pragma unroll 4
    for (int e = 0; e < EDIM; ++e) {
        const float wa = W1[e * HDIM + tid];            // coalesced across tid
        const float wb = W1[(EDIM + e) * HDIM + tid];
        const float h0 = hn_s[0][e], h1 = hn_s[1][e];   // LDS broadcasts
        const float h2 = hn_s[2][e], h3 = hn_s[3][e];
        sa0 = fmaf(h0, wa, sa0); sa1 = fmaf(h1, wa, sa1);
        sa2 = fmaf(h2, wa, sa2); sa3 = fmaf(h3, wa, sa3);
        sb0 = fmaf(h0, wb, sb0); sb1 = fmaf(h1, wb, sb1);
        sb2 = fmaf(h2, wb, sb2); sb3 = fmaf(h3, wb, sb3);
    }
    const float bb1 = b1[tid];
    a_out[(row0 + 0) * HDIM + tid] = sa0;
    a_out[(row0 + 1) * HDIM + tid] = sa1;
    a_out[(row0 + 2) * HDIM + tid] = sa2;
    a_out[(row0 + 3) * HDIM + tid] = sa3;
    b_out[(row0 + 0) * HDIM + tid] = sb0 + bb1;
    b_out[(row0 + 1) * HDIM + tid] = sb1 + bb1;
    b_out[(row0 + 2) * HDIM + tid] = sb2 + bb1;
    b_out[(row0 + 3) * HDIM + tid] = sb3 + bb1;
}

// Fast exact-enough GELU: z * sigmoid(1.5957691*(z + 0.044715 z^3)),
// log2(e) folded; hw v_exp_f32 + v_rcp_f32. |err| vs erf-GELU ~3e-4.
__device__ __forceinline__ float gelu_fast(float z) {
    const float z2 = z * z;
    const float q  = fmaf(-0.10294826f, z2, -2.3022082f);
    const float e  = __builtin_amdgcn_exp2f(z * q);
    const float r  = __builtin_amdgcn_rcpf(1.0f + e);
    return z * r;
}

// Kernel 2: l[b,i,j] = sum_h gelu(a[b,i,h] + b[b,j,h]) * w2[h] + b2
// 32x32 (i,j) tile per 256-thread block, 2x2 outputs per thread.
// H staged in two 128-wide halves: LDS = 2*32*132*4 + 1024 = 34816 B -> 4 blk/CU.
#define HHALF 128
#define PAD 132   // row stride (floats): row start bank = 4r mod 32 -> a-reads
                  // conflict-free, b-reads 2-way (free per m136)

__global__ __launch_bounds__(256) void k_pair(
    const float* __restrict__ a, const float* __restrict__ bpb,
    const float* __restrict__ w2, const float* __restrict__ b2,
    float* __restrict__ out)
{
    __shared__ float a_s[32][PAD];
    __shared__ float b_s[32][PAD];
    __shared__ float w2_s[HDIM];
    const int blk = blockIdx.x;           // bb*256 + bi*16 + bj
    const int bb = blk >> 8;
    const int bi = (blk >> 4) & 15;
    const int bj = blk & 15;
    const int tid = threadIdx.x;

    const float* arow = a + (bb * NDIM + bi * 32) * HDIM;
    const float* brow = bpb + (bb * NDIM + bj * 32) * HDIM;

    if (tid < HDIM / 4) ((float4*)w2_s)[tid] = ((const float4*)w2)[tid];

    const int ti = tid >> 4, tj = tid & 15;
    const float* ap0 = a_s[ti];
    const float* ap1 = a_s[ti + 16];
    const float* bp0 = b_s[tj];
    const float* bp1 = b_s[tj + 16];
    float acc00 = 0.f, acc01 = 0.f, acc10 = 0.f, acc11 = 0.f;

    #pragma unroll
    for (int half = 0; half < 2; ++half) {
        if (half) __syncthreads();        // protect tiles still being read
        const float* ar = arow + half * HHALF;
        const float* br = brow + half * HHALF;
        #pragma unroll
        for (int idx = tid; idx < 32 * (HHALF / 4); idx += 256) {
            const int r = idx >> 5;       // 32 float4 per row-half
            const int c = idx & 31;
            *(float4*)&a_s[r][c * 4] = *(const float4*)(ar + r * HDIM + c * 4);
            *(float4*)&b_s[r][c * 4] = *(const float4*)(br + r * HDIM + c * 4);
        }
        __syncthreads();
        const float* wp = w2_s + half * HHALF;
        #pragma unroll 4
        for (int hh = 0; hh < HHALF; hh += 4) {
            const float4 a0  = *(const float4*)(ap0 + hh);
            const float4 a1  = *(const float4*)(ap1 + hh);
            const float4 b0  = *(const float4*)(bp0 + hh);
            const float4 b1v = *(const float4*)(bp1 + hh);
            const float4 wv  = *(const float4*)(wp + hh);
            acc00 = fmaf(wv.x, gelu_fast(a0.x + b0.x),  acc00);
            acc01 = fmaf(wv.x, gelu_fast(a0.x + b1v.x), acc01);
            acc10 = fmaf(wv.x, gelu_fast(a1.x + b0.x),  acc10);
            acc11 = fmaf(wv.x, gelu_fast(a1.x + b1v.x), acc11);
            acc00 = fmaf(wv.y, gelu_fast(a0.y + b0.y),  acc00);
            acc01 = fmaf(wv.y, gelu_fast(a0.y + b1v.y), acc01);
            acc10 = fmaf(wv.y, gelu_fast(a1.y + b0.y),  acc10);
            acc11 = fmaf(wv.y, gelu_fast(a1.y + b1v.y), acc11);
            acc00 = fmaf(wv.z, gelu_fast(a0.z + b0.z),  acc00);
            acc01 = fmaf(wv.z, gelu_fast(a0.z + b1v.z), acc01);
            acc10 = fmaf(wv.z, gelu_fast(a1.z + b0.z),  acc10);
            acc11 = fmaf(wv.z, gelu_fast(a1.z + b1v.z), acc11);
            acc00 = fmaf(wv.w, gelu_fast(a0.w + b0.w),  acc00);
            acc01 = fmaf(wv.w, gelu_fast(a0.w + b1v.w), acc01);
            acc10 = fmaf(wv.w, gelu_fast(a1.w + b0.w),  acc10);
            acc11 = fmaf(wv.w, gelu_fast(a1.w + b1v.w), acc11);
        }
    }
    const float bias = b2[0];
    const int i0 = bi * 32 + ti;
    const int j0 = bj * 32 + tj;
    float* ob = out + (bb * NDIM + i0) * NDIM;
    ob[j0]      = acc00 + bias;
    ob[j0 + 16] = acc01 + bias;
    ob += 16 * NDIM;
    ob[j0]      = acc10 + bias;
    ob[j0 + 16] = acc11 + bias;
}

// Kernel 3: symmetrize out = 0.5*(l + l^T) via 32x32 LDS tile transpose.
__global__ __launch_bounds__(256) void k_sym(float* __restrict__ out) {
    __shared__ float Ta[32][33];
    __shared__ float Tb[32][33];
    const int blk = blockIdx.x;           // b*256 + ti*16 + tj
    const int b  = blk >> 8;
    const int ti = (blk >> 4) & 15;
    const int tj = blk & 15;
    if (tj < ti) return;                  // upper triangle only (block-uniform)
    float* base = out + b * NDIM * NDIM;
    const int tx = threadIdx.x & 31;
    const int ty = threadIdx.x >> 5;      // 0..7
    #pragma unroll
    for (int r = ty; r < 32; r += 8) {
        Ta[r][tx] = base[(ti * 32 + r) * NDIM + tj * 32 + tx];
        Tb[r][tx] = base[(tj * 32 + r) * NDIM + ti * 32 + tx];
    }
    __syncthreads();
    #pragma unroll
    for (int r = ty; r < 32; r += 8) {
        base[(ti * 32 + r) * NDIM + tj * 32 + tx] = 0.5f * (Ta[r][tx] + Tb[tx][r]);
    }
    if (ti != tj) {
        #pragma unroll
        for (int r = ty; r < 32; r += 8) {
            base[(tj * 32 + r) * NDIM + ti * 32 + tx] = 0.5f * (Tb[r][tx] + Ta[tx][r]);
        }
    }
}

extern "C" void kernel_launch(void* const* d_in, const int* in_sizes, int n_in,
                              void* d_out, int out_size, void* d_ws, size_t ws_size,
                              hipStream_t stream) {
    const float* hptr  = (const float*)d_in[0];
    const float* gamma = (const float*)d_in[1];
    const float* beta  = (const float*)d_in[2];
    const float* W1    = (const float*)d_in[3];
    const float* b1    = (const float*)d_in[4];
    const float* w2    = (const float*)d_in[5];
    const float* b2    = (const float*)d_in[6];
    float* out = (float*)d_out;

    float* a_ws = (float*)d_ws;                          // B*N*H floats = 1 MB
    float* b_ws = a_ws + BDIM * NDIM * HDIM;             // 1 MB more

    k_ln_proj<<<(BDIM * NDIM) / 4, 256, 0, stream>>>(hptr, gamma, beta, W1, b1, a_ws, b_ws);
    k_pair<<<BDIM * 256, 256, 0, stream>>>(a_ws, b_ws, w2, b2, out);
    k_sym<<<BDIM * 256, 256, 0, stream>>>(out);
}

// Round 5
// 49.233 us; speedup vs baseline: 2.3386x; 1.1719x over previous
//
#include <hip/hip_runtime.h>
#include <math.h>

#define EDIM 128
#define HDIM 256
#define NDIM 512
#define BDIM 2
#define LN_EPS 1e-5f

typedef float v2f __attribute__((ext_vector_type(2)));

// Kernel 1: LayerNorm + dual projection, 4 rows per block (1 wave per row).
__global__ __launch_bounds__(256) void k_ln_proj(
    const float* __restrict__ hptr, const float* __restrict__ gamma,
    const float* __restrict__ beta, const float* __restrict__ W1,
    const float* __restrict__ b1, float* __restrict__ a_out,
    float* __restrict__ b_out)
{
    __shared__ float hn_s[4][EDIM];
    const int tid = threadIdx.x;
    const int r = tid >> 6;            // 0..3 (row within block)
    const int lane = tid & 63;
    const int row0 = blockIdx.x * 4;
    const float2 v = *(const float2*)(hptr + (row0 + r) * EDIM + lane * 2);
    float s  = v.x + v.y;
    float ss = v.x * v.x + v.y * v.y;
    #pragma unroll
    for (int k = 32; k >= 1; k >>= 1) {
        s  += __shfl_xor(s, k, 64);
        ss += __shfl_xor(ss, k, 64);
    }
    const float mu  = s * (1.0f / EDIM);
    const float var = ss * (1.0f / EDIM) - mu * mu;
    const float rs  = rsqrtf(var + LN_EPS);
    const float2 g2 = *(const float2*)(gamma + lane * 2);
    const float2 be = *(const float2*)(beta + lane * 2);
    hn_s[r][lane * 2]     = (v.x - mu) * rs * g2.x + be.x;
    hn_s[r][lane * 2 + 1] = (v.y - mu) * rs * g2.y + be.y;
    __syncthreads();
    float sa0 = 0.f, sa1 = 0.f, sa2 = 0.f, sa3 = 0.f;
    float sb0 = 0.f, sb1 = 0.f, sb2 = 0.f, sb3 = 0.f;
    #pragma unroll 4
    for (int e = 0; e < EDIM; ++e) {
        const float wa = W1[e * HDIM + tid];            // coalesced across tid
        const float wb = W1[(EDIM + e) * HDIM + tid];
        const float h0 = hn_s[0][e], h1 = hn_s[1][e];   // LDS broadcasts
        const float h2 = hn_s[2][e], h3 = hn_s[3][e];
        sa0 = fmaf(h0, wa, sa0); sa1 = fmaf(h1, wa, sa1);
        sa2 = fmaf(h2, wa, sa2); sa3 = fmaf(h3, wa, sa3);
        sb0 = fmaf(h0, wb, sb0); sb1 = fmaf(h1, wb, sb1);
        sb2 = fmaf(h2, wb, sb2); sb3 = fmaf(h3, wb, sb3);
    }
    const float bb1 = b1[tid];
    a_out[(row0 + 0) * HDIM + tid] = sa0;
    a_out[(row0 + 1) * HDIM + tid] = sa1;
    a_out[(row0 + 2) * HDIM + tid] = sa2;
    a_out[(row0 + 3) * HDIM + tid] = sa3;
    b_out[(row0 + 0) * HDIM + tid] = sb0 + bb1;
    b_out[(row0 + 1) * HDIM + tid] = sb1 + bb1;
    b_out[(row0 + 2) * HDIM + tid] = sb2 + bb1;
    b_out[(row0 + 3) * HDIM + tid] = sb3 + bb1;
}

// Packed-pair fast GELU: z * sigmoid(1.5957691*(z + 0.044715 z^3)),
// log2(e) folded. Full-rate ops as v_pk_* (2 elems/inst); exp2/rcp scalar.
// Tails: z<<0 -> exp2->inf -> rcp->0 -> g=0; z>>0 -> exp2->0 -> g=z. No NaN.
__device__ __forceinline__ v2f gelu2(v2f z) {
    const v2f c2 = {-0.10294826f, -0.10294826f};
    const v2f c1 = {-2.3022082f, -2.3022082f};
    const v2f z2 = z * z;
    const v2f q  = __builtin_elementwise_fma(c2, z2, c1);
    const v2f p  = z * q;
    v2f e;
    e.x = __builtin_amdgcn_exp2f(p.x);
    e.y = __builtin_amdgcn_exp2f(p.y);
    const v2f d = e + 1.0f;
    v2f r;
    r.x = __builtin_amdgcn_rcpf(d.x);
    r.y = __builtin_amdgcn_rcpf(d.y);
    return z * r;
}

// Kernel 2: l[b,i,j] = sum_h gelu(a[b,i,h] + b[b,j,h]) * w2[h] + b2
// 32x16 (i,j) tile per 256-thread block, 2 outputs/thread (i, i+16).
// H staged in two 128-halves. LDS = (32+16)*132*4 + 1024 = 26368 B.
// Grid = 2*16*32 = 1024 blocks -> 4 blocks/CU, 16 waves/CU.
#define HHALF 128
#define PAD 132   // row start bank = 4r mod 32: a-reads (4 rows/wave) conflict-
                  // free, b-reads 2-way (free per m136)

__global__ __launch_bounds__(256) void k_pair(
    const float* __restrict__ a, const float* __restrict__ bpb,
    const float* __restrict__ w2, const float* __restrict__ b2,
    float* __restrict__ out)
{
    __shared__ float a_s[32][PAD];
    __shared__ float b_s[16][PAD];
    __shared__ float w2_s[HDIM];
    const int blk = blockIdx.x;           // bb*512 + bi*32 + bj
    const int bb = blk >> 9;
    const int bi = (blk >> 5) & 15;       // 16 i-tiles of 32
    const int bj = blk & 31;              // 32 j-tiles of 16
    const int tid = threadIdx.x;

    const float* arow = a + (bb * NDIM + bi * 32) * HDIM;
    const float* brow = bpb + (bb * NDIM + bj * 16) * HDIM;

    if (tid < HDIM / 4) ((float4*)w2_s)[tid] = ((const float4*)w2)[tid];

    const int ti = tid >> 4, tj = tid & 15;
    const float* ap0 = a_s[ti];
    const float* ap1 = a_s[ti + 16];
    const float* bp  = b_s[tj];
    v2f acc0 = {0.f, 0.f}, acc1 = {0.f, 0.f};

    #pragma unroll
    for (int half = 0; half < 2; ++half) {
        if (half) __syncthreads();        // protect tiles still being read
        // stage: a = 32 rows x 32 float4, b = 16 rows x 32 float4 (1536 f4)
        #pragma unroll
        for (int idx = tid; idx < 1536; idx += 256) {
            if (idx < 1024) {
                const int r = idx >> 5, c = idx & 31;
                *(float4*)&a_s[r][c * 4] =
                    *(const float4*)(arow + r * HDIM + half * HHALF + c * 4);
            } else {
                const int k = idx - 1024;
                const int r = k >> 5, c = k & 31;
                *(float4*)&b_s[r][c * 4] =
                    *(const float4*)(brow + r * HDIM + half * HHALF + c * 4);
            }
        }
        __syncthreads();
        const float* wp = w2_s + half * HHALF;
        #pragma unroll 4
        for (int hh = 0; hh < HHALF; hh += 4) {
            const float4 a0 = *(const float4*)(ap0 + hh);
            const float4 a1 = *(const float4*)(ap1 + hh);
            const float4 b0 = *(const float4*)(bp + hh);
            const float4 wv = *(const float4*)(wp + hh);
            const v2f alo0 = {a0.x, a0.y}, ahi0 = {a0.z, a0.w};
            const v2f alo1 = {a1.x, a1.y}, ahi1 = {a1.z, a1.w};
            const v2f blo  = {b0.x, b0.y}, bhi  = {b0.z, b0.w};
            const v2f wlo  = {wv.x, wv.y}, whi  = {wv.z, wv.w};
            acc0 = __builtin_elementwise_fma(wlo, gelu2(alo0 + blo), acc0);
            acc0 = __builtin_elementwise_fma(whi, gelu2(ahi0 + bhi), acc0);
            acc1 = __builtin_elementwise_fma(wlo, gelu2(alo1 + blo), acc1);
            acc1 = __builtin_elementwise_fma(whi, gelu2(ahi1 + bhi), acc1);
        }
    }
    const float bias = b2[0];
    const int i0 = bi * 32 + ti;
    const int j0 = bj * 16 + tj;
    float* ob = out + (bb * NDIM + i0) * NDIM + j0;
    ob[0]         = acc0.x + acc0.y + bias;
    ob[16 * NDIM] = acc1.x + acc1.y + bias;
}

// Kernel 3: symmetrize out = 0.5*(l + l^T) via 32x32 LDS tile transpose.
__global__ __launch_bounds__(256) void k_sym(float* __restrict__ out) {
    __shared__ float Ta[32][33];
    __shared__ float Tb[32][33];
    const int blk = blockIdx.x;           // b*256 + ti*16 + tj
    const int b  = blk >> 8;
    const int ti = (blk >> 4) & 15;
    const int tj = blk & 15;
    if (tj < ti) return;                  // upper triangle only (block-uniform)
    float* base = out + b * NDIM * NDIM;
    const int tx = threadIdx.x & 31;
    const int ty = threadIdx.x >> 5;      // 0..7
    #pragma unroll
    for (int r = ty; r < 32; r += 8) {
        Ta[r][tx] = base[(ti * 32 + r) * NDIM + tj * 32 + tx];
        Tb[r][tx] = base[(tj * 32 + r) * NDIM + ti * 32 + tx];
    }
    __syncthreads();
    #pragma unroll
    for (int r = ty; r < 32; r += 8) {
        base[(ti * 32 + r) * NDIM + tj * 32 + tx] = 0.5f * (Ta[r][tx] + Tb[tx][r]);
    }
    if (ti != tj) {
        #pragma unroll
        for (int r = ty; r < 32; r += 8) {
            base[(tj * 32 + r) * NDIM + ti * 32 + tx] = 0.5f * (Tb[r][tx] + Ta[tx][r]);
        }
    }
}

extern "C" void kernel_launch(void* const* d_in, const int* in_sizes, int n_in,
                              void* d_out, int out_size, void* d_ws, size_t ws_size,
                              hipStream_t stream) {
    const float* hptr  = (const float*)d_in[0];
    const float* gamma = (const float*)d_in[1];
    const float* beta  = (const float*)d_in[2];
    const float* W1    = (const float*)d_in[3];
    const float* b1    = (const float*)d_in[4];
    const float* w2    = (const float*)d_in[5];
    const float* b2    = (const float*)d_in[6];
    float* out = (float*)d_out;

    float* a_ws = (float*)d_ws;                          // B*N*H floats = 1 MB
    float* b_ws = a_ws + BDIM * NDIM * HDIM;             // 1 MB more

    k_ln_proj<<<(BDIM * NDIM) / 4, 256, 0, stream>>>(hptr, gamma, beta, W1, b1, a_ws, b_ws);
    k_pair<<<BDIM * 512, 256, 0, stream>>>(a_ws, b_ws, w2, b2, out);
    k_sym<<<BDIM * 256, 256, 0, stream>>>(out);
}